// Round 7
// baseline (706.803 us; speedup 1.0000x reference)
//
#include <hip/hip_runtime.h>
#include <hip/hip_bf16.h>
#include <math.h>

static const int kN = 32768;   // tokens per batch

typedef __attribute__((ext_vector_type(8))) short short8;   // 8 bf16 = 4 VGPR
typedef __attribute__((ext_vector_type(4))) float f32x4;

typedef __attribute__((address_space(1))) const void* gas_t;
typedef __attribute__((address_space(3))) void* las_t;

// async global->LDS, 16B per lane; LDS dest = wave-uniform base + lane*16
__device__ __forceinline__ void gload16(const void* g, void* l) {
    __builtin_amdgcn_global_load_lds((gas_t)g, (las_t)l, 16, 0, 0);
}

__device__ inline unsigned short f2bf(float x) {
    union { float f; unsigned u; } v; v.f = x;
    unsigned r = v.u + 0x7FFF + ((v.u >> 16) & 1);   // round-to-nearest-even
    return (unsigned short)(r >> 16);
}

// ---------------------------------------------------------------------------
// K_zero: zero split-K accumulators (ws is poisoned 0xAA before every launch).
// ---------------------------------------------------------------------------
__global__ void k_zero(float* __restrict__ p, int n)
{
    int i = blockIdx.x * 256 + threadIdx.x;
    if (i < n) p[i] = 0.f;
}

// ---------------------------------------------------------------------------
// K_prep: WxsT_bf[n][k] = bf16(sum_d Wx[k][h*32+d]*Ws[d][g])  (n = h*32+g)
//         WfxT_bf[n][k] = bf16(Wfx[k][n]);  blog[n] = bx@Ws + bs
// ---------------------------------------------------------------------------
__global__ void k_prep(const float* __restrict__ Wx, const float* __restrict__ Ws,
                       const float* __restrict__ bx, const float* __restrict__ bs,
                       const float* __restrict__ Wfx,
                       unsigned short* __restrict__ WxsT, unsigned short* __restrict__ WfxT,
                       float* __restrict__ blog)
{
    __shared__ float ws_s[1024];           // Ws [32][32]
    int tid = threadIdx.x;
    for (int i = tid; i < 1024; i += 256) ws_s[i] = Ws[i];
    __syncthreads();
    int c = blockIdx.x;                    // K index 0..255
    int h = tid >> 5, g = tid & 31;
    const float* wrow = &Wx[c * 256 + h * 32];
    float s = 0.f;
    #pragma unroll
    for (int d = 0; d < 32; d++) s += wrow[d] * ws_s[d * 32 + g];
    WxsT[tid * 256 + c] = f2bf(s);
    WfxT[tid * 256 + c] = f2bf(Wfx[c * 256 + tid]);
    if (c == 0) {
        float t = 0.f;
        #pragma unroll
        for (int d = 0; d < 32; d++) t += bx[h * 32 + d] * ws_s[d * 32 + g];
        blog[tid] = t + bs[g];
    }
}

// ---------------------------------------------------------------------------
// K1: LayerNorm over C=256. Writes fp32 (residual path) + bf16 (GEMM A).
// ---------------------------------------------------------------------------
__global__ __launch_bounds__(256) void k_ln(const float* __restrict__ fx,
                                            const float* __restrict__ gam,
                                            const float* __restrict__ bet,
                                            float* __restrict__ out,
                                            unsigned short* __restrict__ outb)
{
    int lane = threadIdx.x & 63;
    long row = (long)blockIdx.x * 4 + (threadIdx.x >> 6);
    float4 v = *(const float4*)&fx[row * 256 + lane * 4];
    float s  = v.x + v.y + v.z + v.w;
    float ss = v.x * v.x + v.y * v.y + v.z * v.z + v.w * v.w;
    for (int off = 32; off; off >>= 1) { s += __shfl_down(s, off); ss += __shfl_down(ss, off); }
    s = __shfl(s, 0); ss = __shfl(ss, 0);
    float mu = s * (1.f / 256.f);
    float rstd = rsqrtf(ss * (1.f / 256.f) - mu * mu + 1e-5f);
    float4 gv = *(const float4*)&gam[lane * 4];
    float4 bv = *(const float4*)&bet[lane * 4];
    float4 o;
    o.x = (v.x - mu) * rstd * gv.x + bv.x;
    o.y = (v.y - mu) * rstd * gv.y + bv.y;
    o.z = (v.z - mu) * rstd * gv.z + bv.z;
    o.w = (v.w - mu) * rstd * gv.w + bv.w;
    *(float4*)&out[row * 256 + lane * 4] = o;
    ushort4 ob;
    ob.x = f2bf(o.x); ob.y = f2bf(o.y); ob.z = f2bf(o.z); ob.w = f2bf(o.w);
    *(ushort4*)&outb[row * 256 + lane * 4] = ob;
}

// ---------------------------------------------------------------------------
// K2 v3: fused GEMM [BN,256]x[256,512] bf16 (Wxs|Wfx side by side).
// 256 blocks x 512 thr (8 waves). Wave w owns 64 cols of N=512: w<4 -> Wxs
// (softmax epilogue -> swb), w>=4 -> Wfx (bias epilogue -> fmb).
// B in registers (128 VGPR/wave, loaded once); A via global_load_lds dbuf;
// one barrier per K-step; vectorized epilogue via LDS tile.
// ---------------------------------------------------------------------------
__global__ __launch_bounds__(512, 2) void k_gemm_mid_v3(
    const unsigned short* __restrict__ Abf,
    const unsigned short* __restrict__ WxsT, const unsigned short* __restrict__ WfxT,
    const float* __restrict__ blog, const float* __restrict__ bfx,
    const float* __restrict__ temp,
    unsigned short* __restrict__ swb, unsigned short* __restrict__ fmb)
{
    const int tid = threadIdx.x;
    const int w = tid >> 6, l = tid & 63;
    const int r16 = l & 15, g4 = l >> 4;
    const int blk = blockIdx.x;

    __shared__ unsigned short sA[2][64][32];     // 8 KB, linear 64B rows
    __shared__ unsigned short etile[64][264];    // 33.8 KB epilogue staging

    // ---- B fragments in registers (wave's 64 cols x K=256) ----
    const unsigned short* WT = (w < 4) ? (WxsT + (size_t)(w * 64) * 256)
                                       : (WfxT + (size_t)((w - 4) * 64) * 256);
    short8 bq[4][8];
    #pragma unroll
    for (int nf = 0; nf < 4; nf++)
        #pragma unroll
        for (int ks = 0; ks < 8; ks++)
            bq[nf][ks] = *(const short8*)&WT[(size_t)(nf * 16 + r16) * 256 + ks * 32 + g4 * 8];

    // ---- epilogue constants ----
    float rt0 = 0.f, rt1 = 0.f, bl0 = 0.f, bl1 = 0.f, bl2 = 0.f, bl3 = 0.f;
    float bf0 = 0.f, bf1 = 0.f, bf2 = 0.f, bf3 = 0.f;
    if (w < 4) {
        rt0 = 1.0f / temp[w * 2]; rt1 = 1.0f / temp[w * 2 + 1];
        bl0 = blog[w * 64 + r16];      bl1 = blog[w * 64 + 16 + r16];
        bl2 = blog[w * 64 + 32 + r16]; bl3 = blog[w * 64 + 48 + r16];
    } else {
        bf0 = bfx[(w - 4) * 64 + r16];      bf1 = bfx[(w - 4) * 64 + 16 + r16];
        bf2 = bfx[(w - 4) * 64 + 32 + r16]; bf3 = bfx[(w - 4) * 64 + 48 + r16];
    }

    // ---- prologue: stage tile 0, k-step 0 into buf 0 (waves 0-3, 16 rows each)
    long row0 = (long)blk * 8 * 64;
    if (w < 4)
        gload16(&Abf[(row0 + w * 16 + (l >> 2)) * 256 + (l & 3) * 8], &sA[0][w * 16][0]);
    __syncthreads();

    for (int j = 0; j < 8; j++) {
        row0 = (long)(blk * 8 + j) * 64;
        f32x4 acc[4][4];
        #pragma unroll
        for (int mf = 0; mf < 4; mf++)
            #pragma unroll
            for (int nf = 0; nf < 4; nf++) acc[mf][nf] = (f32x4){0.f, 0.f, 0.f, 0.f};

        #pragma unroll
        for (int t = 0; t < 8; t++) {
            if (w < 4) {                       // issue next stage before compute
                if (t < 7)
                    gload16(&Abf[(row0 + w * 16 + (l >> 2)) * 256 + (t + 1) * 32 + (l & 3) * 8],
                            &sA[(t + 1) & 1][w * 16][0]);
                else if (j < 7)
                    gload16(&Abf[(row0 + 64 + w * 16 + (l >> 2)) * 256 + (l & 3) * 8],
                            &sA[0][w * 16][0]);
            }
            short8 af[4];
            #pragma unroll
            for (int mf = 0; mf < 4; mf++)
                af[mf] = *(const short8*)&sA[t & 1][mf * 16 + r16][g4 * 8];
            #pragma unroll
            for (int mf = 0; mf < 4; mf++)
                #pragma unroll
                for (int nf = 0; nf < 4; nf++)
                    acc[mf][nf] = __builtin_amdgcn_mfma_f32_16x16x32_bf16(
                        af[mf], bq[nf][t], acc[mf][nf], 0, 0, 0);
            __syncthreads();
        }

        // ---- epilogue: 2 rounds through LDS, vectorized stores ----
        #pragma unroll
        for (int half = 0; half < 2; half++) {
            if ((w >> 2) == half) {
                if (half == 0) {
                    #pragma unroll
                    for (int mf = 0; mf < 4; mf++)
                        #pragma unroll
                        for (int ri = 0; ri < 4; ri++) {
                            int rloc = mf * 16 + g4 * 4 + ri;
                            // head 2w
                            float z0 = (acc[mf][0][ri] + bl0) * rt0;
                            float z1 = (acc[mf][1][ri] + bl1) * rt0;
                            float m = fmaxf(z0, z1);
                            m = fmaxf(m, __shfl_xor(m, 1)); m = fmaxf(m, __shfl_xor(m, 2));
                            m = fmaxf(m, __shfl_xor(m, 4)); m = fmaxf(m, __shfl_xor(m, 8));
                            float e0 = __expf(z0 - m), e1 = __expf(z1 - m);
                            float sm = e0 + e1;
                            sm += __shfl_xor(sm, 1); sm += __shfl_xor(sm, 2);
                            sm += __shfl_xor(sm, 4); sm += __shfl_xor(sm, 8);
                            float inv = 1.0f / sm;
                            etile[rloc][w * 64 + r16]      = f2bf(e0 * inv);
                            etile[rloc][w * 64 + 16 + r16] = f2bf(e1 * inv);
                            // head 2w+1
                            z0 = (acc[mf][2][ri] + bl2) * rt1;
                            z1 = (acc[mf][3][ri] + bl3) * rt1;
                            m = fmaxf(z0, z1);
                            m = fmaxf(m, __shfl_xor(m, 1)); m = fmaxf(m, __shfl_xor(m, 2));
                            m = fmaxf(m, __shfl_xor(m, 4)); m = fmaxf(m, __shfl_xor(m, 8));
                            e0 = __expf(z0 - m); e1 = __expf(z1 - m);
                            sm = e0 + e1;
                            sm += __shfl_xor(sm, 1); sm += __shfl_xor(sm, 2);
                            sm += __shfl_xor(sm, 4); sm += __shfl_xor(sm, 8);
                            inv = 1.0f / sm;
                            etile[rloc][w * 64 + 32 + r16] = f2bf(e0 * inv);
                            etile[rloc][w * 64 + 48 + r16] = f2bf(e1 * inv);
                        }
                } else {
                    int c0 = (w - 4) * 64;
                    #pragma unroll
                    for (int mf = 0; mf < 4; mf++)
                        #pragma unroll
                        for (int ri = 0; ri < 4; ri++) {
                            int rloc = mf * 16 + g4 * 4 + ri;
                            etile[rloc][c0 + r16]      = f2bf(acc[mf][0][ri] + bf0);
                            etile[rloc][c0 + 16 + r16] = f2bf(acc[mf][1][ri] + bf1);
                            etile[rloc][c0 + 32 + r16] = f2bf(acc[mf][2][ri] + bf2);
                            etile[rloc][c0 + 48 + r16] = f2bf(acc[mf][3][ri] + bf3);
                        }
                }
            }
            __syncthreads();
            unsigned short* dst = half ? fmb : swb;
            #pragma unroll
            for (int k = 0; k < 4; k++) {
                int c = tid + 512 * k;                 // 2048 chunks of 8 u16
                int row = c >> 5, col = (c & 31) * 8;
                *(uint4*)&dst[(row0 + row) * 256 + col] = *(const uint4*)&etile[row][col];
            }
            __syncthreads();
        }
    }
}

// ---------------------------------------------------------------------------
// K3: slice_token/slice_norm reduction (bf16 inputs, fp32 accumulate).
// ---------------------------------------------------------------------------
__global__ __launch_bounds__(256) void k_reduce(
    const unsigned short* __restrict__ swb, const unsigned short* __restrict__ fmb,
    float* __restrict__ tok_acc, float* __restrict__ nrm_acc)
{
    const int bh = blockIdx.y;
    const int b = bh >> 3, h = bh & 7;
    const int tid = threadIdx.x;
    const int g = tid >> 3, dq = tid & 7, d0 = dq * 4;
    __shared__ float sw_t[64][36];
    __shared__ float fm_t[64][36];
    float4 acc = make_float4(0.f, 0.f, 0.f, 0.f);
    float nacc = 0.f;
    long base = (long)b * kN + (long)blockIdx.x * 2048;
    const int r = tid >> 2, q = tid & 3;

    for (int t0 = 0; t0 < 2048; t0 += 64) {
        long ga = (base + t0 + r) * 256 + h * 32 + q * 8;
        uint4 wv = *(const uint4*)&swb[ga];
        uint4 fv = *(const uint4*)&fmb[ga];
        __syncthreads();
        const unsigned* wu = (const unsigned*)&wv;
        const unsigned* fu = (const unsigned*)&fv;
        #pragma unroll
        for (int e = 0; e < 4; e++) {
            union { unsigned u; float f; } lo, hi;
            lo.u = wu[e] << 16; hi.u = wu[e] & 0xFFFF0000u;
            sw_t[r][q * 8 + 2 * e] = lo.f; sw_t[r][q * 8 + 2 * e + 1] = hi.f;
            lo.u = fu[e] << 16; hi.u = fu[e] & 0xFFFF0000u;
            fm_t[r][q * 8 + 2 * e] = lo.f; fm_t[r][q * 8 + 2 * e + 1] = hi.f;
        }
        __syncthreads();
        #pragma unroll 4
        for (int rr = 0; rr < 64; rr++) {
            float wgt = sw_t[rr][g];
            float4 f = *(const float4*)&fm_t[rr][d0];
            acc.x += wgt * f.x; acc.y += wgt * f.y; acc.z += wgt * f.z; acc.w += wgt * f.w;
            if (dq == 0) nacc += wgt;
        }
    }
    float* ta = &tok_acc[(bh * 32 + g) * 32 + d0];
    atomicAdd(&ta[0], acc.x); atomicAdd(&ta[1], acc.y);
    atomicAdd(&ta[2], acc.z); atomicAdd(&ta[3], acc.w);
    if (dq == 0) atomicAdd(&nrm_acc[bh * 32 + g], nacc);
}

// ---------------------------------------------------------------------------
// K4: per-(b,h) token block; writes tokWoT bf16 TRANSPOSED [b][c][hg].
// ---------------------------------------------------------------------------
__global__ __launch_bounds__(256) void k_tokens(
    const float* __restrict__ tok_acc, const float* __restrict__ nrm_acc,
    const float* __restrict__ Wq, const float* __restrict__ Wk, const float* __restrict__ Wv,
    const float* __restrict__ tlng, const float* __restrict__ tlnb,
    const float* __restrict__ W1, const float* __restrict__ b1,
    const float* __restrict__ W2, const float* __restrict__ b2,
    const float* __restrict__ Wo, unsigned short* __restrict__ tokWoT)
{
    const int bh = blockIdx.x, b = bh >> 3, h = bh & 7;
    const int tid = threadIdx.x;
    const int g = tid >> 3, dq = tid & 7, d0 = dq * 4;
    __shared__ float t[32][32], qm[32][32], km[32][32], vm[32][32];
    __shared__ float att[32][33], ot[32][32], hn[32][32], tk[32][32];
    __shared__ float h1[32][128];
    __shared__ float mu_s[32], rs_s[32];

    {
        float inv = 1.0f / (nrm_acc[bh * 32 + g] + 1e-5f);
        #pragma unroll
        for (int u = 0; u < 4; u++)
            t[g][d0 + u] = tok_acc[(bh * 32 + g) * 32 + d0 + u] * inv;
    }
    __syncthreads();
    #pragma unroll
    for (int u = 0; u < 4; u++) {
        int d = d0 + u;
        float sq = 0.f, sk = 0.f, sv = 0.f;
        for (int dd = 0; dd < 32; dd++) {
            float tv = t[g][dd];
            sq = fmaf(tv, Wq[dd * 32 + d], sq);
            sk = fmaf(tv, Wk[dd * 32 + d], sk);
            sv = fmaf(tv, Wv[dd * 32 + d], sv);
        }
        qm[g][d] = sq; km[g][d] = sk; vm[g][d] = sv;
    }
    __syncthreads();
    const float SC = 0.17677669529663687f;
    #pragma unroll
    for (int u = 0; u < 4; u++) {
        int gk = d0 + u;
        float s = 0.f;
        for (int dd = 0; dd < 32; dd++) s = fmaf(qm[g][dd], km[gk][dd], s);
        att[g][gk] = s * SC;
    }
    __syncthreads();
    if (tid < 32) {
        float m = -1e30f;
        for (int j = 0; j < 32; j++) m = fmaxf(m, att[tid][j]);
        float s = 0.f;
        for (int j = 0; j < 32; j++) { float e = expf(att[tid][j] - m); att[tid][j] = e; s += e; }
        float inv = 1.0f / s;
        for (int j = 0; j < 32; j++) att[tid][j] *= inv;
    }
    __syncthreads();
    #pragma unroll
    for (int u = 0; u < 4; u++) {
        int d = d0 + u;
        float s = 0.f;
        for (int kk = 0; kk < 32; kk++) s = fmaf(att[g][kk], vm[kk][d], s);
        ot[g][d] = s + t[g][d];
    }
    __syncthreads();
    if (tid < 32) {
        float s = 0.f, ss = 0.f;
        for (int dd = 0; dd < 32; dd++) { float v = ot[tid][dd]; s += v; ss += v * v; }
        float mu = s * (1.f / 32.f);
        mu_s[tid] = mu;
        rs_s[tid] = rsqrtf(ss * (1.f / 32.f) - mu * mu + 1e-5f);
    }
    __syncthreads();
    #pragma unroll
    for (int u = 0; u < 4; u++) {
        int d = d0 + u;
        hn[g][d] = (ot[g][d] - mu_s[g]) * rs_s[g] * tlng[d] + tlnb[d];
    }
    __syncthreads();
    for (int c = dq * 16; c < dq * 16 + 16; c++) {
        float s = b1[c];
        for (int dd = 0; dd < 32; dd++) s = fmaf(hn[g][dd], W1[dd * 128 + c], s);
        h1[g][c] = 0.5f * s * (1.0f + erff(s * 0.70710678118654752f));
    }
    __syncthreads();
    #pragma unroll
    for (int u = 0; u < 4; u++) {
        int d = d0 + u;
        float s = b2[d];
        for (int c = 0; c < 128; c++) s = fmaf(h1[g][c], W2[c * 32 + d], s);
        tk[g][d] = s + ot[g][d];
    }
    __syncthreads();
    {
        int c0 = dq * 32;
        for (int c = c0; c < c0 + 32; c++) {
            float s = 0.f;
            for (int dd = 0; dd < 32; dd++) s = fmaf(tk[g][dd], Wo[(h * 32 + dd) * 256 + c], s);
            tokWoT[(size_t)b * 65536 + c * 256 + h * 32 + g] = f2bf(s);
        }
    }
}

// ---------------------------------------------------------------------------
// K5 v3: out = slice_w @ tokWoT[b] + bo + fx_norm.
// 256 blocks x 512 thr; wave = (row-half, col-slice). B in regs; A dbuf via
// global_load_lds; vectorized fp32 epilogue via LDS.
// ---------------------------------------------------------------------------
__global__ __launch_bounds__(512, 2) void k_gemm_out_v3(
    const unsigned short* __restrict__ Abf,       // slice_w bf16 [BN][256]
    const unsigned short* __restrict__ tokWoT,    // [b][n=256][k=256] bf16
    const float* __restrict__ bo, const float* __restrict__ fx_norm,
    float* __restrict__ out)
{
    const int tid = threadIdx.x;
    const int w = tid >> 6, l = tid & 63;
    const int r16 = l & 15, g4 = l >> 4;
    const int blk = blockIdx.x;
    const int wc = w & 3, wrh = w >> 2;           // col-slice, row-half
    const int b = blk >> 6;                       // 64 blocks per batch

    __shared__ unsigned short sA[2][128][32];     // 16 KB
    __shared__ float etf[64][260];                // 66.6 KB epilogue staging

    const unsigned short* WT = tokWoT + (size_t)b * 65536 + (size_t)(wc * 64) * 256;
    short8 bq[4][8];
    #pragma unroll
    for (int nf = 0; nf < 4; nf++)
        #pragma unroll
        for (int ks = 0; ks < 8; ks++)
            bq[nf][ks] = *(const short8*)&WT[(size_t)(nf * 16 + r16) * 256 + ks * 32 + g4 * 8];

    long row0 = (long)blk * 4 * 128;
    gload16(&Abf[(row0 + w * 16 + (l >> 2)) * 256 + (l & 3) * 8], &sA[0][w * 16][0]);
    __syncthreads();

    for (int j = 0; j < 4; j++) {
        row0 = (long)(blk * 4 + j) * 128;
        f32x4 acc[4][4];
        #pragma unroll
        for (int mf = 0; mf < 4; mf++)
            #pragma unroll
            for (int nf = 0; nf < 4; nf++) acc[mf][nf] = (f32x4){0.f, 0.f, 0.f, 0.f};

        #pragma unroll
        for (int t = 0; t < 8; t++) {
            if (t < 7)
                gload16(&Abf[(row0 + w * 16 + (l >> 2)) * 256 + (t + 1) * 32 + (l & 3) * 8],
                        &sA[(t + 1) & 1][w * 16][0]);
            else if (j < 3)
                gload16(&Abf[(row0 + 128 + w * 16 + (l >> 2)) * 256 + (l & 3) * 8],
                        &sA[0][w * 16][0]);
            short8 af[4];
            #pragma unroll
            for (int mf = 0; mf < 4; mf++)
                af[mf] = *(const short8*)&sA[t & 1][wrh * 64 + mf * 16 + r16][g4 * 8];
            #pragma unroll
            for (int mf = 0; mf < 4; mf++)
                #pragma unroll
                for (int nf = 0; nf < 4; nf++)
                    acc[mf][nf] = __builtin_amdgcn_mfma_f32_16x16x32_bf16(
                        af[mf], bq[nf][t], acc[mf][nf], 0, 0, 0);
            __syncthreads();
        }

        #pragma unroll
        for (int half = 0; half < 2; half++) {
            if (wrh == half) {
                #pragma unroll
                for (int mf = 0; mf < 4; mf++)
                    #pragma unroll
                    for (int nf = 0; nf < 4; nf++)
                        #pragma unroll
                        for (int ri = 0; ri < 4; ri++)
                            etf[mf * 16 + g4 * 4 + ri][wc * 64 + nf * 16 + r16] = acc[mf][nf][ri];
            }
            __syncthreads();
            #pragma unroll
            for (int k = 0; k < 8; k++) {
                int c = tid + 512 * k;                 // 4096 chunks of 4 f32
                int row = c >> 6, col = (c & 63) * 4;
                float4 v = *(const float4*)&etf[row][col];
                float4 bb = *(const float4*)&bo[col];
                long gr = row0 + half * 64 + row;
                float4 fn = *(const float4*)&fx_norm[gr * 256 + col];
                float4 o;
                o.x = v.x + bb.x + fn.x;
                o.y = v.y + bb.y + fn.y;
                o.z = v.z + bb.z + fn.z;
                o.w = v.w + bb.w + fn.w;
                *(float4*)&out[gr * 256 + col] = o;
            }
            __syncthreads();
        }
    }
}

// ---------------------------------------------------------------------------
extern "C" void kernel_launch(void* const* d_in, const int* in_sizes, int n_in,
                              void* d_out, int out_size, void* d_ws, size_t ws_size,
                              hipStream_t stream)
{
    const float* fx   = (const float*)d_in[0];
    const float* ln_g = (const float*)d_in[1];
    const float* ln_b = (const float*)d_in[2];
    const float* Wx   = (const float*)d_in[3];
    const float* bx   = (const float*)d_in[4];
    const float* Wfx  = (const float*)d_in[5];
    const float* bfx  = (const float*)d_in[6];
    const float* Ws   = (const float*)d_in[7];
    const float* bs   = (const float*)d_in[8];
    const float* temp = (const float*)d_in[9];
    const float* Wq   = (const float*)d_in[10];
    const float* Wk   = (const float*)d_in[11];
    const float* Wv   = (const float*)d_in[12];
    const float* tlng = (const float*)d_in[13];
    const float* tlnb = (const float*)d_in[14];
    const float* W1   = (const float*)d_in[15];
    const float* b1   = (const float*)d_in[16];
    const float* W2   = (const float*)d_in[17];
    const float* b2   = (const float*)d_in[18];
    const float* Wo   = (const float*)d_in[19];
    const float* bo   = (const float*)d_in[20];
    float* out = (float*)d_out;

    char* ws = (char*)d_ws;
    float*          fx_norm = (float*)(ws + 0);                  // 134217728
    unsigned short* fxn_bf  = (unsigned short*)(ws + 134217728); //  67108864
    unsigned short* swb     = (unsigned short*)(ws + 201326592); //  67108864
    unsigned short* fmb     = (unsigned short*)(ws + 268435456); //  67108864
    unsigned short* WxsT    = (unsigned short*)(ws + 335544320); //    131072
    unsigned short* WfxT    = (unsigned short*)(ws + 335675392); //    131072
    float*          blog    = (float*)(ws + 335806464);          //      1024
    float*          tok_acc = (float*)(ws + 335807488);          //    131072
    float*          nrm_acc = (float*)(ws + 335938560);          //      4096
    unsigned short* tokWoT  = (unsigned short*)(ws + 335942656); //    524288
    if (ws_size < 336466944ULL) return;

    k_prep<<<256, 256, 0, stream>>>(Wx, Ws, bx, bs, Wfx, WxsT, WfxT, blog);
    k_ln<<<32768, 256, 0, stream>>>(fx, ln_g, ln_b, fx_norm, fxn_bf);
    k_gemm_mid_v3<<<256, 512, 0, stream>>>(fxn_bf, WxsT, WfxT, blog, bfx, temp, swb, fmb);
    k_zero<<<132, 256, 0, stream>>>(tok_acc, 33792);
    k_reduce<<<dim3(16, 32), 256, 0, stream>>>(swb, fmb, tok_acc, nrm_acc);
    k_tokens<<<32, 256, 0, stream>>>(tok_acc, nrm_acc, Wq, Wk, Wv, tlng, tlnb,
                                     W1, b1, W2, b2, Wo, tokWoT);
    k_gemm_out_v3<<<256, 512, 0, stream>>>(swb, tokWoT, bo, fx_norm, out);
}